// Round 7
// baseline (2110.912 us; speedup 1.0000x reference)
//
#include <hip/hip_runtime.h>

#define S 2048
#define Hd 3072
#define NE 4
#define Id 8192
#define BK 64
#define RMAX 5120   // 20 tiles * 256

typedef __attribute__((ext_vector_type(8))) short short8;
typedef __attribute__((ext_vector_type(4))) float f32x4;

__device__ __forceinline__ unsigned short f2bf(float f) {
    unsigned u = __builtin_bit_cast(unsigned, f);
    u += 0x7FFFu + ((u >> 16) & 1u);   // RNE
    return (unsigned short)(u >> 16);
}

__device__ __forceinline__ void gload_lds16(const void* g, void* l) {
    __builtin_amdgcn_global_load_lds(
        (const __attribute__((address_space(1))) unsigned int*)g,
        (__attribute__((address_space(3))) unsigned int*)l,
        16, 0, 0);
}

#define BAR() __builtin_amdgcn_s_barrier();
#define LGKM0_SB() { asm volatile("s_waitcnt lgkmcnt(0)" ::: "memory"); __builtin_amdgcn_sched_barrier(0); }
#define VMC_SB(n) { asm volatile("s_waitcnt vmcnt(" #n ")" ::: "memory"); __builtin_amdgcn_sched_barrier(0); }

// ---------------- gating: logits -> softmax -> top2 ----------------
__global__ void gate_topk_kernel(const float* __restrict__ x,
                                 const float* __restrict__ gw,
                                 int* __restrict__ tok_e,
                                 float* __restrict__ tok_v) {
    const int t = blockIdx.x;
    const int lane = threadIdx.x & 63;
    const int wave = threadIdx.x >> 6;
    __shared__ float logits[NE];
    const float* xp = x + (size_t)t * Hd;
    const float* wp = gw + (size_t)wave * Hd;
    float s = 0.f;
    for (int h = lane; h < Hd; h += 64) s += xp[h] * wp[h];
#pragma unroll
    for (int o = 32; o > 0; o >>= 1) s += __shfl_xor(s, o);
    if (lane == 0) logits[wave] = s;
    __syncthreads();
    if (threadIdx.x == 0) {
        float m = logits[0];
#pragma unroll
        for (int e = 1; e < NE; e++) m = fmaxf(m, logits[e]);
        float p[NE]; float sum = 0.f;
#pragma unroll
        for (int e = 0; e < NE; e++) { p[e] = expf(logits[e] - m); sum += p[e]; }
        float inv = 1.f / sum;
#pragma unroll
        for (int e = 0; e < NE; e++) p[e] *= inv;
        int e0 = 0; float v0 = p[0];
#pragma unroll
        for (int e = 1; e < NE; e++) if (p[e] > v0) { e0 = e; v0 = p[e]; }
        int e1 = -1; float v1 = -1.f;
#pragma unroll
        for (int e = 0; e < NE; e++) if (e != e0 && p[e] > v1) { e1 = e; v1 = p[e]; }
        tok_e[t * 2] = e0; tok_e[t * 2 + 1] = e1;
        tok_v[t * 2] = v0; tok_v[t * 2 + 1] = v1;
    }
}

// ---------------- routing: 256-padded per-expert row lists ----------------
__global__ void route_kernel(const int* __restrict__ tok_e, const float* __restrict__ tok_v,
                             int* __restrict__ row_token, float* __restrict__ row_gate,
                             int* __restrict__ offsets) {
    __shared__ int cnt[NE], cur[NE], offs[NE + 1];
    const int tid = threadIdx.x;
    if (tid < NE) { cnt[tid] = 0; cur[tid] = 0; }
    __syncthreads();
    for (int i = tid; i < S * 2; i += 256) atomicAdd(&cnt[tok_e[i]], 1);
    __syncthreads();
    if (tid == 0) {
        int o = 0;
        for (int e = 0; e < NE; e++) { offs[e] = o; o += (cnt[e] + 255) / 256 * 256; }
        offs[NE] = o;
        for (int e = 0; e <= NE; e++) offsets[e] = offs[e];
    }
    __syncthreads();
    for (int r = tid; r < RMAX; r += 256) { row_token[r] = 0; row_gate[r] = 0.f; }
    __syncthreads();
    for (int i = tid; i < S * 2; i += 256) {
        int e = tok_e[i];
        int pos = atomicAdd(&cur[e], 1);
        int r = offs[e] + pos;
        row_token[r] = i >> 1;
        row_gate[r] = tok_v[i];
    }
}

// ---------------- f32 -> bf16 (grid-stride, 16 elems/thread) — x only ----------------
__global__ void cvt_bf16_kernel(const float* __restrict__ src,
                                unsigned short* __restrict__ dst, size_t n16) {
    size_t stride = (size_t)gridDim.x * blockDim.x;
    for (size_t i = (size_t)blockIdx.x * blockDim.x + threadIdx.x; i < n16; i += stride) {
        size_t b = i * 16;
        f32x4 a0 = *(const f32x4*)(src + b);
        f32x4 a1 = *(const f32x4*)(src + b + 4);
        f32x4 a2 = *(const f32x4*)(src + b + 8);
        f32x4 a3 = *(const f32x4*)(src + b + 12);
        union { unsigned short u[8]; short8 v; } o0, o1;
#pragma unroll
        for (int j = 0; j < 4; j++) {
            o0.u[j] = f2bf(a0[j]); o0.u[4 + j] = f2bf(a1[j]);
            o1.u[j] = f2bf(a2[j]); o1.u[4 + j] = f2bf(a3[j]);
        }
        *(short8*)(dst + b) = o0.v;
        *(short8*)(dst + b + 8) = o1.v;
    }
}

// ============ 256x256 8-phase GEMMs; A via global_load_lds, B reg-staged f32->bf16 ============
// Per-tile VMEM FIFO (per thread): entering t: A4(t+1) in flight.
// P0: +B4a(t+1) ; P1: +B4b(t+1) +A0_2(t+2) ; P2: vmcnt(6) [drains A4(t+1),B4a] write-a, +A1_2(t+2)
// P3: vmcnt(4) [drains B4b; leaves A4(t+2)] write-b. lgkm0 before tile-end barrier.

#define ST_A0(buf, k) { gload_lds16(aP[0] + (k), &Ald[buf][raD[0]][0]); gload_lds16(aP[1] + (k), &Ald[buf][raD[1]][0]); }
#define ST_A1(buf, k) { gload_lds16(aP[2] + (k), &Ald[buf][raD[2]][0]); gload_lds16(aP[3] + (k), &Ald[buf][raD[3]][0]); }

#define READ_AFL(b) _Pragma("unroll") for (int mi = 0; mi < 4; mi++) _Pragma("unroll") for (int kk = 0; kk < 2; kk++) { \
    int row = wm * 128 + mi * 16 + c16; int slot = ((kk << 2) + c4) ^ l7; \
    afL[mi][kk] = *(const short8*)&Ald[b][row][slot * 8]; }
#define READ_AFH(b) _Pragma("unroll") for (int mi = 0; mi < 4; mi++) _Pragma("unroll") for (int kk = 0; kk < 2; kk++) { \
    int row = wm * 128 + 64 + mi * 16 + c16; int slot = ((kk << 2) + c4) ^ l7; \
    afH[mi][kk] = *(const short8*)&Ald[b][row][slot * 8]; }
#define READ_BFL(b) _Pragma("unroll") for (int n = 0; n < 2; n++) _Pragma("unroll") for (int kk = 0; kk < 2; kk++) { \
    int row = wn * 64 + n * 16 + c16; int slot = ((kk << 2) + c4) ^ l7; \
    bfL[n][kk] = *(const short8*)&Bld[b][row][slot * 8]; }
#define READ_BFH(b) _Pragma("unroll") for (int n = 0; n < 2; n++) _Pragma("unroll") for (int kk = 0; kk < 2; kk++) { \
    int row = wn * 64 + 32 + n * 16 + c16; int slot = ((kk << 2) + c4) ^ l7; \
    bfH[n][kk] = *(const short8*)&Bld[b][row][slot * 8]; }

#define MFMA_Q(AF, BF, MO, NO) _Pragma("unroll") for (int mi = 0; mi < 4; mi++) \
    _Pragma("unroll") for (int n = 0; n < 2; n++) _Pragma("unroll") for (int kk = 0; kk < 2; kk++) \
        acc[mi + MO][n + NO] = __builtin_amdgcn_mfma_f32_16x16x32_bf16(AF[mi][kk], BF[n][kk], acc[mi + MO][n + NO], 0, 0, 0);

#define LOAD_B_HALF(h, k) { \
    bv[4*(h)+0] = *(const f32x4*)(bsrc + (k) + 16*(h)); \
    bv[4*(h)+1] = *(const f32x4*)(bsrc + (k) + 16*(h) + 4); \
    bv[4*(h)+2] = *(const f32x4*)(bsrc + (k) + 16*(h) + 8); \
    bv[4*(h)+3] = *(const f32x4*)(bsrc + (k) + 16*(h) + 12); }

#define WRITE_B_HALF(buf, h) { \
    union { unsigned short u[8]; short8 v8; } w0_, w1_; \
    _Pragma("unroll") for (int q = 0; q < 4; q++) { \
        w0_.u[q] = f2bf(bv[4*(h)+0][q]); w0_.u[4+q] = f2bf(bv[4*(h)+1][q]); \
        w1_.u[q] = f2bf(bv[4*(h)+2][q]); w1_.u[4+q] = f2bf(bv[4*(h)+3][q]); } \
    *(short8*)&Bld[buf][colB][(((halfB<<2) + 2*(h) + 0) ^ cswB) * 8] = w0_.v8; \
    *(short8*)&Bld[buf][colB][(((halfB<<2) + 2*(h) + 1) ^ cswB) * 8] = w1_.v8; }

#define KTILE_BODY(bR, bW, kN, kNN) { \
    short8 afL[4][2], afH[4][2], bfL[2][2], bfH[2][2]; \
    /* P0: issue B-a(t+1); read afL,bfL; MFMA q00 */ \
    LOAD_B_HALF(0, kN); \
    __builtin_amdgcn_sched_barrier(0); \
    READ_AFL(bR); READ_BFL(bR); \
    BAR(); LGKM0_SB(); \
    __builtin_amdgcn_s_setprio(1); MFMA_Q(afL, bfL, 0, 0); __builtin_amdgcn_s_setprio(0); \
    BAR(); \
    /* P1: issue B-b(t+1); DMA A0(t+2); read afH; MFMA q10 */ \
    LOAD_B_HALF(1, kN); \
    ST_A0(bR, kNN); \
    __builtin_amdgcn_sched_barrier(0); \
    READ_AFH(bR); \
    BAR(); LGKM0_SB(); \
    __builtin_amdgcn_s_setprio(1); MFMA_Q(afH, bfL, 4, 0); __builtin_amdgcn_s_setprio(0); \
    BAR(); \
    /* P2: drain B-a; cvt+write-a; DMA A1(t+2); read bfH; MFMA q01 */ \
    VMC_SB(6); \
    WRITE_B_HALF(bW, 0); \
    ST_A1(bR, kNN); \
    READ_BFH(bR); \
    BAR(); LGKM0_SB(); \
    __builtin_amdgcn_s_setprio(1); MFMA_Q(afL, bfH, 0, 2); __builtin_amdgcn_s_setprio(0); \
    BAR(); \
    /* P3: drain B-b; cvt+write-b; MFMA q11 */ \
    VMC_SB(4); \
    WRITE_B_HALF(bW, 1); \
    __builtin_amdgcn_s_setprio(1); MFMA_Q(afH, bfH, 4, 2); __builtin_amdgcn_s_setprio(0); \
    LGKM0_SB(); BAR(); }

// GEMM1: hidden = swiglu(x_rows . WguT); 1D grid 1280, xcd-clustered by ct
__global__ __launch_bounds__(512, 2)
void gemm1_8p_kernel(const unsigned short* __restrict__ xb,
                     const float* __restrict__ wgu,
                     const int* __restrict__ row_token,
                     const int* __restrict__ offsets,
                     unsigned short* __restrict__ hidden) {
    __shared__ unsigned short Ald[2][256][BK];
    __shared__ unsigned short Bld[2][256][BK];

    const int id = blockIdx.x;
    const int xcd = id & 7, jj = id >> 3;     // 160 per XCD
    const int ct = xcd * 8 + jj / 20;         // 64 ct panels, 8 per XCD
    const int rt = jj % 20;
    const int rbase = rt * 256;
    if (rbase >= offsets[4]) return;
    int e = 3;
    if (rbase < offsets[1]) e = 0;
    else if (rbase < offsets[2]) e = 1;
    else if (rbase < offsets[3]) e = 2;

    const int tid = threadIdx.x;
    const int l = tid & 63;
    const int w = tid >> 6;
    const int wm = w >> 2, wn = w & 3;
    const int lr = l >> 3;
    const int g8 = ((l & 7) ^ lr) << 3;
    const int c16 = l & 15, c4 = l >> 4, l7 = l & 7;

    const unsigned short* aP[4]; int raD[4];
#pragma unroll
    for (int j = 0; j < 4; j++) {
        int r0 = w * 8 + (j & 1) * 128 + (j >> 1) * 64;
        raD[j] = r0;
        int tok = row_token[rbase + r0 + lr];
        aP[j] = xb + (size_t)tok * Hd + g8;
    }
    // B reg-staging source (f32 weights, gate/up interleaved at 16-row frags)
    const int colB = tid >> 1, halfB = tid & 1, cswB = colB & 7;
    const int fB = colB >> 4;
    const size_t wrB = (size_t)e * (2 * Id) + (size_t)(fB & 1) * Id
                     + (size_t)ct * 128 + ((fB >> 1) << 4) + (colB & 15);
    const float* bsrc = wgu + wrB * Hd + halfB * 32;

    f32x4 acc[8][4];
#pragma unroll
    for (int mi = 0; mi < 8; mi++)
#pragma unroll
        for (int n = 0; n < 4; n++) acc[mi][n] = (f32x4)0.f;
    f32x4 bv[8];

    // prologue: A(0),B(0),A(1); vmcnt(4) leaves A(1) in flight
    ST_A0(0, 0); ST_A1(0, 0);
    LOAD_B_HALF(0, 0); LOAD_B_HALF(1, 0);
    __builtin_amdgcn_sched_barrier(0);
    ST_A0(1, BK); ST_A1(1, BK);
    VMC_SB(4);
    WRITE_B_HALF(0, 0); WRITE_B_HALF(0, 1);
    LGKM0_SB(); BAR();

    const int nt = Hd / BK;   // 48
    for (int t = 0; t < nt; ++t) {
        const int bR = t & 1, bW = bR ^ 1;
        const int kN  = (t + 1 < nt ? t + 1 : nt - 1) * BK;
        const int kNN = (t + 2 < nt ? t + 2 : nt - 1) * BK;
        KTILE_BODY(bR, bW, kN, kNN);
    }
    asm volatile("s_waitcnt vmcnt(0)" ::: "memory");

    // SwiGLU epilogue: acc[.][2p]=gate, acc[.][2p+1]=up (same cols)
#pragma unroll
    for (int mi = 0; mi < 8; mi++)
#pragma unroll
        for (int np = 0; np < 2; np++) {
            int col = ct * 128 + (wn * 2 + np) * 16 + c16;
#pragma unroll
            for (int q = 0; q < 4; q++) {
                int row = rbase + wm * 128 + mi * 16 + c4 * 4 + q;
                float gv = acc[mi][2 * np][q], uv = acc[mi][2 * np + 1][q];
                float h = uv * gv / (1.f + expf(-gv));
                hidden[(size_t)row * Id + col] = f2bf(h);
            }
        }
}

// GEMM2: out[token] += gate * (hidden_rows . WdT); 256x256, 1D grid 240 xcd-clustered
__global__ __launch_bounds__(512, 2)
void gemm2_8p_kernel(const unsigned short* __restrict__ hidden,
                     const float* __restrict__ wd,
                     const int* __restrict__ row_token,
                     const float* __restrict__ row_gate,
                     const int* __restrict__ offsets,
                     float* __restrict__ out) {
    __shared__ unsigned short Ald[2][256][BK];
    __shared__ unsigned short Bld[2][256][BK];

    const int id = blockIdx.x;
    const int xcd = id & 7, jj = id >> 3;     // 30 per XCD
    const int j12 = xcd * 30 + jj;
    const int ct = j12 / 20;                  // 12 ct panels
    const int rt = j12 % 20;
    const int rbase = rt * 256;
    if (rbase >= offsets[4]) return;
    int e = 3;
    if (rbase < offsets[1]) e = 0;
    else if (rbase < offsets[2]) e = 1;
    else if (rbase < offsets[3]) e = 2;

    const int tid = threadIdx.x;
    const int l = tid & 63;
    const int w = tid >> 6;
    const int wm = w >> 2, wn = w & 3;
    const int lr = l >> 3;
    const int g8 = ((l & 7) ^ lr) << 3;
    const int c16 = l & 15, c4 = l >> 4, l7 = l & 7;

    const unsigned short* aP[4]; int raD[4];
#pragma unroll
    for (int j = 0; j < 4; j++) {
        int r0 = w * 8 + (j & 1) * 128 + (j >> 1) * 64;
        raD[j] = r0;
        aP[j] = hidden + (size_t)(rbase + r0 + lr) * Id + g8;
    }
    const int colB = tid >> 1, halfB = tid & 1, cswB = colB & 7;
    const float* bsrc = wd + ((size_t)e * Hd + (size_t)ct * 256 + colB) * Id + halfB * 32;

    f32x4 acc[8][4];
#pragma unroll
    for (int mi = 0; mi < 8; mi++)
#pragma unroll
        for (int n = 0; n < 4; n++) acc[mi][n] = (f32x4)0.f;
    f32x4 bv[8];

    ST_A0(0, 0); ST_A1(0, 0);
    LOAD_B_HALF(0, 0); LOAD_B_HALF(1, 0);
    __builtin_amdgcn_sched_barrier(0);
    ST_A0(1, BK); ST_A1(1, BK);
    VMC_SB(4);
    WRITE_B_HALF(0, 0); WRITE_B_HALF(0, 1);
    LGKM0_SB(); BAR();

    const int nt = Id / BK;   // 128
    for (int t = 0; t < nt; ++t) {
        const int bR = t & 1, bW = bR ^ 1;
        const int kN  = (t + 1 < nt ? t + 1 : nt - 1) * BK;
        const int kNN = (t + 2 < nt ? t + 2 : nt - 1) * BK;
        KTILE_BODY(bR, bW, kN, kNN);
    }
    asm volatile("s_waitcnt vmcnt(0)" ::: "memory");

#pragma unroll
    for (int mi = 0; mi < 8; mi++)
#pragma unroll
        for (int n = 0; n < 4; n++) {
            int col = ct * 256 + wn * 64 + n * 16 + c16;
#pragma unroll
            for (int q = 0; q < 4; q++) {
                int r = rbase + wm * 128 + mi * 16 + c4 * 4 + q;
                int tok = row_token[r];
                float gv = row_gate[r];
                if (gv != 0.f)
                    atomicAdd(&out[(size_t)tok * Hd + col], gv * acc[mi][n][q]);
            }
        }
}

// ================= f32-weight fused GEMMs (fallback if ws too small) =================

__global__ __launch_bounds__(256, 2)
void gemm1_f32_kernel(const unsigned short* __restrict__ xb,
                      const float* __restrict__ wgu,
                      const int* __restrict__ row_token,
                      const int* __restrict__ offsets,
                      unsigned short* __restrict__ hidden) {
    __shared__ unsigned short As[128][BK];
    __shared__ unsigned short Bg[128][BK];
    __shared__ unsigned short Bu[128][BK];

    const int rt = blockIdx.x, ct = blockIdx.y;
    const int rbase = rt * 128;
    if (rbase >= offsets[4]) return;
    int e = 3;
    if (rbase < offsets[1]) e = 0;
    else if (rbase < offsets[2]) e = 1;
    else if (rbase < offsets[3]) e = 2;

    const int tid = threadIdx.x;
    const int lane = tid & 63;
    const int wave = tid >> 6;
    const int wm = wave >> 1, wn = wave & 1;

    const unsigned short* asrc[4];
#pragma unroll
    for (int i2 = 0; i2 < 4; i2++) {
        int sgi = i2 * 4 + wave;
        int row = sgi * 8 + (lane >> 3);
        int g = (lane & 7) ^ (row & 7);
        int tok = row_token[rbase + row];
        asrc[i2] = xb + (size_t)tok * Hd + g * 8;
    }
    const int col = tid >> 1;
    const int half = tid & 1;
    const size_t grow = (size_t)e * (2 * Id) + (size_t)ct * 128 + col;
    const float* bsrc_g = wgu + grow * Hd + half * 32;
    const float* bsrc_u = wgu + (grow + (size_t)Id) * Hd + half * 32;
    const int csw = col & 7;

    f32x4 accg[4][4], accu[4][4];
#pragma unroll
    for (int m = 0; m < 4; m++)
#pragma unroll
        for (int n = 0; n < 4; n++) { accg[m][n] = (f32x4)0.f; accu[m][n] = (f32x4)0.f; }

    for (int k0 = 0; k0 < Hd; k0 += BK) {
        __syncthreads();
#pragma unroll
        for (int i2 = 0; i2 < 4; i2++) {
            int sgi = i2 * 4 + wave;
            gload_lds16(asrc[i2] + k0, &As[sgi * 8][0]);
        }
        {
            const float* pg = bsrc_g + k0;
            const float* pu = bsrc_u + k0;
            f32x4 vg[8], vu[8];
#pragma unroll
            for (int j = 0; j < 8; j++) vg[j] = *(const f32x4*)(pg + j * 4);
#pragma unroll
            for (int j = 0; j < 8; j++) vu[j] = *(const f32x4*)(pu + j * 4);
#pragma unroll
            for (int j = 0; j < 4; j++) {
                union { unsigned short u[8]; short8 v8; } wg_, wu_;
#pragma unroll
                for (int q = 0; q < 4; q++) {
                    wg_.u[q] = f2bf(vg[2 * j][q]); wg_.u[4 + q] = f2bf(vg[2 * j + 1][q]);
                    wu_.u[q] = f2bf(vu[2 * j][q]); wu_.u[4 + q] = f2bf(vu[2 * j + 1][q]);
                }
                int gs = (half * 4 + j) ^ csw;
                *(short8*)&Bg[col][gs * 8] = wg_.v8;
                *(short8*)&Bu[col][gs * 8] = wu_.v8;
            }
        }
        __syncthreads();
#pragma unroll
        for (int kk = 0; kk < 2; kk++) {
            short8 af[4], bgf[4], buf_[4];
#pragma unroll
            for (int m = 0; m < 4; m++) {
                int r = wm * 64 + m * 16 + (lane & 15);
                int slot = (kk * 4 + (lane >> 4)) ^ (r & 7);
                af[m] = *(const short8*)&As[r][slot * 8];
            }
#pragma unroll
            for (int n = 0; n < 4; n++) {
                int c = wn * 64 + n * 16 + (lane & 15);
                int slot = (kk * 4 + (lane >> 4)) ^ (c & 7);
                bgf[n] = *(const short8*)&Bg[c][slot * 8];
                buf_[n] = *(const short8*)&Bu[c][slot * 8];
            }
#pragma unroll
            for (int m = 0; m < 4; m++)
#pragma unroll
                for (int n = 0; n < 4; n++) {
                    accg[m][n] = __builtin_amdgcn_mfma_f32_16x16x32_bf16(af[m], bgf[n], accg[m][n], 0, 0, 0);
                    accu[m][n] = __builtin_amdgcn_mfma_f32_16x16x32_bf16(af[m], buf_[n], accu[m][n], 0, 0, 0);
                }
        }
    }
#pragma unroll
    for (int m = 0; m < 4; m++) {
#pragma unroll
        for (int n = 0; n < 4; n++) {
            int c = ct * 128 + wn * 64 + n * 16 + (lane & 15);
#pragma unroll
            for (int q = 0; q < 4; q++) {
                int r = rbase + wm * 64 + m * 16 + (lane >> 4) * 4 + q;
                float g = accg[m][n][q], u = accu[m][n][q];
                float hval = u * g / (1.f + expf(-g));
                hidden[(size_t)r * Id + c] = f2bf(hval);
            }
        }
    }
}

__global__ __launch_bounds__(256, 2)
void gemm2_f32_kernel(const unsigned short* __restrict__ hidden,
                      const float* __restrict__ wd,
                      const int* __restrict__ row_token,
                      const float* __restrict__ row_gate,
                      const int* __restrict__ offsets,
                      float* __restrict__ out) {
    __shared__ unsigned short As[128][BK];
    __shared__ unsigned short Bs[128][BK];

    const int rt = blockIdx.x, ct = blockIdx.y;
    const int rbase = rt * 128;
    if (rbase >= offsets[4]) return;
    int e = 3;
    if (rbase < offsets[1]) e = 0;
    else if (rbase < offsets[2]) e = 1;
    else if (rbase < offsets[3]) e = 2;

    const int tid = threadIdx.x;
    const int lane = tid & 63;
    const int wave = tid >> 6;
    const int wm = wave >> 1, wn = wave & 1;

    const unsigned short* asrc[4];
#pragma unroll
    for (int i2 = 0; i2 < 4; i2++) {
        int sgi = i2 * 4 + wave;
        int row = sgi * 8 + (lane >> 3);
        int g = (lane & 7) ^ (row & 7);
        asrc[i2] = hidden + (size_t)(rbase + row) * Id + g * 8;
    }
    const int col = tid >> 1;
    const int half = tid & 1;
    const float* bsrc = wd + ((size_t)e * Hd + (size_t)ct * 128 + col) * Id + half * 32;
    const int csw = col & 7;

    f32x4 acc[4][4];
#pragma unroll
    for (int m = 0; m < 4; m++)
#pragma unroll
        for (int n = 0; n < 4; n++) acc[m][n] = (f32x4)0.f;

    for (int k0 = 0; k0 < Id; k0 += BK) {
        __syncthreads();
#pragma unroll
        for (int i2 = 0; i2 < 4; i2++) {
            int sgi = i2 * 4 + wave;
            gload_lds16(asrc[i2] + k0, &As[sgi * 8][0]);
        }
        {
            const float* pb = bsrc + k0;
            f32x4 vb[8];
#pragma unroll
            for (int j = 0; j < 8; j++) vb[j] = *(const f32x4*)(pb + j * 4);
#pragma unroll
            for (int j = 0; j < 4; j++) {
                union { unsigned short u[8]; short8 v8; } wb_;
#pragma unroll
                for (int q = 0; q < 4; q++) {
                    wb_.u[q] = f2bf(vb[2 * j][q]); wb_.u[4 + q] = f2bf(vb[2 * j + 1][q]);
                }
                int gs = (half * 4 + j) ^ csw;
                *(short8*)&Bs[col][gs * 8] = wb_.v8;
            }
        }
        __syncthreads();
#pragma unroll
        for (int kk = 0; kk < 2; kk++) {
            short8 af[4], bf[4];
#pragma unroll
            for (int m = 0; m < 4; m++) {
                int r = wm * 64 + m * 16 + (lane & 15);
                int slot = (kk * 4 + (lane >> 4)) ^ (r & 7);
                af[m] = *(const short8*)&As[r][slot * 8];
            }
#pragma unroll
            for (int n = 0; n < 4; n++) {
                int c = wn * 64 + n * 16 + (lane & 15);
                int slot = (kk * 4 + (lane >> 4)) ^ (c & 7);
                bf[n] = *(const short8*)&Bs[c][slot * 8];
            }
#pragma unroll
            for (int m = 0; m < 4; m++)
#pragma unroll
                for (int n = 0; n < 4; n++)
                    acc[m][n] = __builtin_amdgcn_mfma_f32_16x16x32_bf16(af[m], bf[n], acc[m][n], 0, 0, 0);
        }
    }
#pragma unroll
    for (int m = 0; m < 4; m++) {
#pragma unroll
        for (int n = 0; n < 4; n++) {
            int c = ct * 128 + wn * 64 + n * 16 + (lane & 15);
#pragma unroll
            for (int q = 0; q < 4; q++) {
                int r = rbase + wm * 64 + m * 16 + (lane >> 4) * 4 + q;
                int tok = row_token[r];
                float gv = row_gate[r];
                if (gv != 0.f)
                    atomicAdd(&out[(size_t)tok * Hd + c], gv * acc[m][n][q]);
            }
        }
    }
}

extern "C" void kernel_launch(void* const* d_in, const int* in_sizes, int n_in,
                              void* d_out, int out_size, void* d_ws, size_t ws_size,
                              hipStream_t stream) {
    const float* x   = (const float*)d_in[0];
    const float* gw  = (const float*)d_in[1];
    const float* wgu = (const float*)d_in[2];
    const float* wd  = (const float*)d_in[3];
    float* out = (float*)d_out;

    char* ws = (char*)d_ws;
    size_t o = 0;
    auto alloc = [&](size_t bytes) { void* p = ws + o; o = (o + bytes + 255) & ~(size_t)255; return p; };
    unsigned short* xb      = (unsigned short*)alloc((size_t)S * Hd * 2);
    unsigned short* hidden  = (unsigned short*)alloc((size_t)RMAX * Id * 2);
    int*   row_token = (int*)alloc(RMAX * 4);
    float* row_gate  = (float*)alloc(RMAX * 4);
    int*   offsets   = (int*)alloc(8 * 4);
    int*   tok_e     = (int*)alloc(S * 2 * 4);
    float* tok_v     = (float*)alloc(S * 2 * 4);
    const bool big = (ws_size >= o);

    hipMemsetAsync(d_out, 0, (size_t)S * Hd * 4, stream);
    gate_topk_kernel<<<S, 256, 0, stream>>>(x, gw, tok_e, tok_v);
    route_kernel<<<1, 256, 0, stream>>>(tok_e, tok_v, row_token, row_gate, offsets);
    cvt_bf16_kernel<<<1024, 256, 0, stream>>>(x, xb, (size_t)S * Hd / 16);

    if (big) {
        gemm1_8p_kernel<<<1280, 512, 0, stream>>>(xb, wgu, row_token, offsets, hidden);
        gemm2_8p_kernel<<<240, 512, 0, stream>>>(hidden, wd, row_token, row_gate, offsets, out);
    } else {
        gemm1_f32_kernel<<<dim3(RMAX / 128, Id / 128), 256, 0, stream>>>(
            xb, wgu, row_token, offsets, hidden);
        gemm2_f32_kernel<<<dim3(RMAX / 128, Hd / 128), 256, 0, stream>>>(
            hidden, wd, row_token, row_gate, offsets, out);
    }
}

// Round 8
// 1179.588 us; speedup vs baseline: 1.7895x; 1.7895x over previous
//
#include <hip/hip_runtime.h>

#define S 2048
#define Hd 3072
#define NE 4
#define Id 8192
#define BK 64
#define RMAX 5120   // 20 tiles * 256

#define CVT1_BLKS 3072
#define CVTX_BLKS 128
#define GATE_BLKS 2048
#define CVTW_BLKS 256

typedef __attribute__((ext_vector_type(8))) short short8;
typedef __attribute__((ext_vector_type(4))) float f32x4;

__device__ __forceinline__ unsigned short f2bf(float f) {
    unsigned u = __builtin_bit_cast(unsigned, f);
    u += 0x7FFFu + ((u >> 16) & 1u);   // RNE
    return (unsigned short)(u >> 16);
}

__device__ __forceinline__ void gload_lds16(const void* g, void* l) {
    __builtin_amdgcn_global_load_lds(
        (const __attribute__((address_space(1))) unsigned int*)g,
        (__attribute__((address_space(3))) unsigned int*)l,
        16, 0, 0);
}

#define BAR() __builtin_amdgcn_s_barrier();
#define LGKM0_SB() { asm volatile("s_waitcnt lgkmcnt(0)" ::: "memory"); __builtin_amdgcn_sched_barrier(0); }
#define VM6_SB()  { asm volatile("s_waitcnt vmcnt(6)" ::: "memory"); __builtin_amdgcn_sched_barrier(0); }

// grid-strided f32->bf16, 16 elems/thread/iter
__device__ __forceinline__ void cvt_range(const float* __restrict__ src,
                                          unsigned short* __restrict__ dst,
                                          size_t n16, int bid, int nblk, int nthr) {
    size_t stride = (size_t)nblk * nthr;
    for (size_t i = (size_t)bid * nthr + threadIdx.x; i < n16; i += stride) {
        size_t b = i * 16;
        f32x4 a0 = *(const f32x4*)(src + b);
        f32x4 a1 = *(const f32x4*)(src + b + 4);
        f32x4 a2 = *(const f32x4*)(src + b + 8);
        f32x4 a3 = *(const f32x4*)(src + b + 12);
        union { unsigned short u[8]; short8 v; } o0, o1;
#pragma unroll
        for (int j = 0; j < 4; j++) {
            o0.u[j] = f2bf(a0[j]); o0.u[4 + j] = f2bf(a1[j]);
            o1.u[j] = f2bf(a2[j]); o1.u[4 + j] = f2bf(a3[j]);
        }
        *(short8*)(dst + b) = o0.v;
        *(short8*)(dst + b + 8) = o1.v;
    }
}

// ---------------- K1: fused pre-pass (cvt_wgu || cvt_x || gating) ----------------
__global__ __launch_bounds__(256)
void fused_pre_kernel(const float* __restrict__ x,
                      const float* __restrict__ gw,
                      const float* __restrict__ wgu,
                      unsigned short* __restrict__ wgu_b,
                      unsigned short* __restrict__ xb,
                      int* __restrict__ tok_e,
                      float* __restrict__ tok_v) {
    const int bid = blockIdx.x;
    if (bid < CVT1_BLKS) {                                  // wgu -> bf16 (critical path)
        cvt_range(wgu, wgu_b, (size_t)NE * 2 * Id * Hd / 16, bid, CVT1_BLKS, 256);
        return;
    }
    if (bid < CVT1_BLKS + CVTX_BLKS) {                      // x -> bf16
        cvt_range(x, xb, (size_t)S * Hd / 16, bid - CVT1_BLKS, CVTX_BLKS, 256);
        return;
    }
    // gating for token t
    const int t = bid - CVT1_BLKS - CVTX_BLKS;
    const int lane = threadIdx.x & 63;
    const int wave = threadIdx.x >> 6;
    __shared__ float logits[NE];
    const float* xp = x + (size_t)t * Hd;
    const float* wp = gw + (size_t)wave * Hd;
    float s = 0.f;
    for (int h = lane; h < Hd; h += 64) s += xp[h] * wp[h];
#pragma unroll
    for (int o = 32; o > 0; o >>= 1) s += __shfl_xor(s, o);
    if (lane == 0) logits[wave] = s;
    __syncthreads();
    if (threadIdx.x == 0) {
        float m = logits[0];
#pragma unroll
        for (int e = 1; e < NE; e++) m = fmaxf(m, logits[e]);
        float p[NE]; float sum = 0.f;
#pragma unroll
        for (int e = 0; e < NE; e++) { p[e] = expf(logits[e] - m); sum += p[e]; }
        float inv = 1.f / sum;
#pragma unroll
        for (int e = 0; e < NE; e++) p[e] *= inv;
        int e0 = 0; float v0 = p[0];
#pragma unroll
        for (int e = 1; e < NE; e++) if (p[e] > v0) { e0 = e; v0 = p[e]; }
        int e1 = -1; float v1 = -1.f;
#pragma unroll
        for (int e = 0; e < NE; e++) if (e != e0 && p[e] > v1) { e1 = e; v1 = p[e]; }
        tok_e[t * 2] = e0; tok_e[t * 2 + 1] = e1;
        tok_v[t * 2] = v0; tok_v[t * 2 + 1] = v1;
    }
}

// standalone gating (fallback path only)
__global__ void gate_topk_kernel(const float* __restrict__ x,
                                 const float* __restrict__ gw,
                                 int* __restrict__ tok_e,
                                 float* __restrict__ tok_v) {
    const int t = blockIdx.x;
    const int lane = threadIdx.x & 63;
    const int wave = threadIdx.x >> 6;
    __shared__ float logits[NE];
    const float* xp = x + (size_t)t * Hd;
    const float* wp = gw + (size_t)wave * Hd;
    float s = 0.f;
    for (int h = lane; h < Hd; h += 64) s += xp[h] * wp[h];
#pragma unroll
    for (int o = 32; o > 0; o >>= 1) s += __shfl_xor(s, o);
    if (lane == 0) logits[wave] = s;
    __syncthreads();
    if (threadIdx.x == 0) {
        float m = logits[0];
#pragma unroll
        for (int e = 1; e < NE; e++) m = fmaxf(m, logits[e]);
        float p[NE]; float sum = 0.f;
#pragma unroll
        for (int e = 0; e < NE; e++) { p[e] = expf(logits[e] - m); sum += p[e]; }
        float inv = 1.f / sum;
#pragma unroll
        for (int e = 0; e < NE; e++) p[e] *= inv;
        int e0 = 0; float v0 = p[0];
#pragma unroll
        for (int e = 1; e < NE; e++) if (p[e] > v0) { e0 = e; v0 = p[e]; }
        int e1 = -1; float v1 = -1.f;
#pragma unroll
        for (int e = 0; e < NE; e++) if (e != e0 && p[e] > v1) { e1 = e; v1 = p[e]; }
        tok_e[t * 2] = e0; tok_e[t * 2 + 1] = e1;
        tok_v[t * 2] = v0; tok_v[t * 2 + 1] = v1;
    }
}

// ---------------- routing: 256-padded per-expert row lists ----------------
__global__ void route_kernel(const int* __restrict__ tok_e, const float* __restrict__ tok_v,
                             int* __restrict__ row_token, float* __restrict__ row_gate,
                             int* __restrict__ offsets) {
    __shared__ int cnt[NE], cur[NE], offs[NE + 1];
    const int tid = threadIdx.x;
    if (tid < NE) { cnt[tid] = 0; cur[tid] = 0; }
    __syncthreads();
    for (int i = tid; i < S * 2; i += 256) atomicAdd(&cnt[tok_e[i]], 1);
    __syncthreads();
    if (tid == 0) {
        int o = 0;
        for (int e = 0; e < NE; e++) { offs[e] = o; o += (cnt[e] + 255) / 256 * 256; }
        offs[NE] = o;
        for (int e = 0; e <= NE; e++) offsets[e] = offs[e];
    }
    __syncthreads();
    for (int r = tid; r < RMAX; r += 256) { row_token[r] = 0; row_gate[r] = 0.f; }
    __syncthreads();
    for (int i = tid; i < S * 2; i += 256) {
        int e = tok_e[i];
        int pos = atomicAdd(&cur[e], 1);
        int r = offs[e] + pos;
        row_token[r] = i >> 1;
        row_gate[r] = tok_v[i];
    }
}

// ---------------- f32 -> bf16 standalone (fallback x-conversion) ----------------
__global__ void cvt_bf16_kernel(const float* __restrict__ src,
                                unsigned short* __restrict__ dst, size_t n16) {
    cvt_range(src, dst, n16, blockIdx.x, gridDim.x, blockDim.x);
}

// ================= 256x256 8-phase GEMMs, counted vmcnt (r6 proven schedule) =================

#define ST_A0(buf, k) { gload_lds16(aP[0] + (k), &Ald[buf][raD[0]][0]); gload_lds16(aP[1] + (k), &Ald[buf][raD[1]][0]); }
#define ST_A1(buf, k) { gload_lds16(aP[2] + (k), &Ald[buf][raD[2]][0]); gload_lds16(aP[3] + (k), &Ald[buf][raD[3]][0]); }
#define ST_B0(buf, k) { gload_lds16(bP[0] + (k), &Bld[buf][rbD[0]][0]); gload_lds16(bP[1] + (k), &Bld[buf][rbD[1]][0]); }
#define ST_B1(buf, k) { gload_lds16(bP[2] + (k), &Bld[buf][rbD[2]][0]); gload_lds16(bP[3] + (k), &Bld[buf][rbD[3]][0]); }

#define READ_AFL(b) _Pragma("unroll") for (int mi = 0; mi < 4; mi++) _Pragma("unroll") for (int kk = 0; kk < 2; kk++) { \
    int row = wm * 128 + mi * 16 + c16; int slot = ((kk << 2) + c4) ^ l7; \
    afL[mi][kk] = *(const short8*)&Ald[b][row][slot * 8]; }
#define READ_AFH(b) _Pragma("unroll") for (int mi = 0; mi < 4; mi++) _Pragma("unroll") for (int kk = 0; kk < 2; kk++) { \
    int row = wm * 128 + 64 + mi * 16 + c16; int slot = ((kk << 2) + c4) ^ l7; \
    afH[mi][kk] = *(const short8*)&Ald[b][row][slot * 8]; }
#define READ_BFL(b) _Pragma("unroll") for (int n = 0; n < 2; n++) _Pragma("unroll") for (int kk = 0; kk < 2; kk++) { \
    int row = wn * 64 + n * 16 + c16; int slot = ((kk << 2) + c4) ^ l7; \
    bfL[n][kk] = *(const short8*)&Bld[b][row][slot * 8]; }
#define READ_BFH(b) _Pragma("unroll") for (int n = 0; n < 2; n++) _Pragma("unroll") for (int kk = 0; kk < 2; kk++) { \
    int row = wn * 64 + 32 + n * 16 + c16; int slot = ((kk << 2) + c4) ^ l7; \
    bfH[n][kk] = *(const short8*)&Bld[b][row][slot * 8]; }

#define MFMA_Q(AF, BF, MO, NO) _Pragma("unroll") for (int mi = 0; mi < 4; mi++) \
    _Pragma("unroll") for (int n = 0; n < 2; n++) _Pragma("unroll") for (int kk = 0; kk < 2; kk++) \
        acc[mi + MO][n + NO] = __builtin_amdgcn_mfma_f32_16x16x32_bf16(AF[mi][kk], BF[n][kk], acc[mi + MO][n + NO], 0, 0, 0);

#define KTILE_BODY(bR, bW, kN, kNN) { \
    short8 afL[4][2], afH[4][2], bfL[2][2], bfH[2][2]; \
    /* P0 */ \
    READ_AFL(bR); READ_BFL(bR); \
    ST_B1(bW, kN); \
    BAR(); LGKM0_SB(); \
    __builtin_amdgcn_s_setprio(1); MFMA_Q(afL, bfL, 0, 0); __builtin_amdgcn_s_setprio(0); \
    BAR(); \
    /* P1 */ \
    READ_AFH(bR); \
    ST_A0(bR, kNN); \
    BAR(); LGKM0_SB(); \
    __builtin_amdgcn_s_setprio(1); MFMA_Q(afH, bfL, 4, 0); __builtin_amdgcn_s_setprio(0); \
    BAR(); \
    /* P2 */ \
    READ_BFH(bR); \
    ST_B0(bR, kNN); \
    BAR(); LGKM0_SB(); \
    __builtin_amdgcn_s_setprio(1); MFMA_Q(afL, bfH, 0, 2); __builtin_amdgcn_s_setprio(0); \
    BAR(); \
    /* P3 */ \
    ST_A1(bR, kNN); \
    BAR(); \
    __builtin_amdgcn_s_setprio(1); MFMA_Q(afH, bfH, 4, 2); __builtin_amdgcn_s_setprio(0); \
    VM6_SB(); BAR(); }

// GEMM1: head blocks convert wd->bf16; rest = swiglu GEMM, xcd-clustered by ct
__global__ __launch_bounds__(512, 2)
void gemm1_8p_kernel(const unsigned short* __restrict__ xb,
                     const unsigned short* __restrict__ wgu_b,
                     const float* __restrict__ wd,
                     unsigned short* __restrict__ wd_b,
                     const int* __restrict__ row_token,
                     const int* __restrict__ offsets,
                     unsigned short* __restrict__ hidden) {
    __shared__ unsigned short Ald[2][256][BK];
    __shared__ unsigned short Bld[2][256][BK];

    if (blockIdx.x < CVTW_BLKS) {      // off-critical-path wd conversion rides gemm1's spare BW
        cvt_range(wd, wd_b, (size_t)NE * Hd * Id / 16, blockIdx.x, CVTW_BLKS, 512);
        return;
    }
    const int id = blockIdx.x - CVTW_BLKS;   // 256 ≡ 0 (mod 8): xcd mapping preserved
    const int xcd = id & 7, jj = id >> 3;    // 160 per XCD
    const int ct = xcd * 8 + jj / 20;        // 64 ct panels, 8 per XCD
    const int rt = jj % 20;
    const int rbase = rt * 256;
    if (rbase >= offsets[4]) return;
    int e = 3;
    if (rbase < offsets[1]) e = 0;
    else if (rbase < offsets[2]) e = 1;
    else if (rbase < offsets[3]) e = 2;

    const int tid = threadIdx.x;
    const int l = tid & 63;
    const int w = tid >> 6;
    const int wm = w >> 2, wn = w & 3;
    const int lr = l >> 3;
    const int g8 = ((l & 7) ^ lr) << 3;
    const int c16 = l & 15, c4 = l >> 4, l7 = l & 7;

    const unsigned short* aP[4]; int raD[4];
    const unsigned short* bP[4]; int rbD[4];
#pragma unroll
    for (int j = 0; j < 4; j++) {
        int r0 = w * 8 + (j & 1) * 128 + (j >> 1) * 64;
        raD[j] = r0;
        int tok = row_token[rbase + r0 + lr];
        aP[j] = xb + (size_t)tok * Hd + g8;
        int rb0 = (w & 3) * 8 + (w >> 2) * 64 + (j & 1) * 128 + (j >> 1) * 32;
        rbD[j] = rb0;
        int brow = rb0 + lr;
        int f = brow >> 4;
        size_t wr = (size_t)e * (2 * Id) + (size_t)(f & 1) * Id
                  + (size_t)ct * 128 + ((f >> 1) << 4) + (brow & 15);
        bP[j] = wgu_b + wr * Hd + g8;
    }

    f32x4 acc[8][4];
#pragma unroll
    for (int mi = 0; mi < 8; mi++)
#pragma unroll
        for (int n = 0; n < 4; n++) acc[mi][n] = (f32x4)0.f;

    // prologue: 7 half-tiles; vmcnt(6) lands tile0
    ST_A0(0, 0); ST_B0(0, 0); ST_A1(0, 0); ST_B1(0, 0);
    ST_A0(1, BK); ST_B0(1, BK); ST_A1(1, BK);
    VM6_SB(); BAR();

    const int nt = Hd / BK;   // 48
    for (int t = 0; t < nt; ++t) {
        const int bR = t & 1, bW = bR ^ 1;
        const int kN  = (t + 1 < nt ? t + 1 : nt - 1) * BK;
        const int kNN = (t + 2 < nt ? t + 2 : nt - 1) * BK;
        KTILE_BODY(bR, bW, kN, kNN);
    }
    asm volatile("s_waitcnt vmcnt(0)" ::: "memory");

    // SwiGLU epilogue: acc[.][2p]=gate, acc[.][2p+1]=up (same cols)
#pragma unroll
    for (int mi = 0; mi < 8; mi++)
#pragma unroll
        for (int np = 0; np < 2; np++) {
            int col = ct * 128 + (wn * 2 + np) * 16 + c16;
#pragma unroll
            for (int q = 0; q < 4; q++) {
                int row = rbase + wm * 128 + mi * 16 + c4 * 4 + q;
                float gv = acc[mi][2 * np][q], uv = acc[mi][2 * np + 1][q];
                float h = uv * gv / (1.f + expf(-gv));
                hidden[(size_t)row * Id + col] = f2bf(h);
            }
        }
}

// GEMM2: out[token] += gate * (hidden_rows . WdT); 256x256, grid (20, 12)
__global__ __launch_bounds__(512, 2)
void gemm2_8p_kernel(const unsigned short* __restrict__ hidden,
                     const unsigned short* __restrict__ wd_b,
                     const int* __restrict__ row_token,
                     const float* __restrict__ row_gate,
                     const int* __restrict__ offsets,
                     float* __restrict__ out) {
    __shared__ unsigned short Ald[2][256][BK];
    __shared__ unsigned short Bld[2][256][BK];

    const int rt = blockIdx.x, ct = blockIdx.y;
    const int rbase = rt * 256;
    if (rbase >= offsets[4]) return;
    int e = 3;
    if (rbase < offsets[1]) e = 0;
    else if (rbase < offsets[2]) e = 1;
    else if (rbase < offsets[3]) e = 2;

    const int tid = threadIdx.x;
    const int l = tid & 63;
    const int w = tid >> 6;
    const int wm = w >> 2, wn = w & 3;
    const int lr = l >> 3;
    const int g8 = ((l & 7) ^ lr) << 3;
    const int c16 = l & 15, c4 = l >> 4, l7 = l & 7;

    const unsigned short* aP[4]; int raD[4];
    const unsigned short* bP[4]; int rbD[4];
#pragma unroll
    for (int j = 0; j < 4; j++) {
        int r0 = w * 8 + (j & 1) * 128 + (j >> 1) * 64;
        raD[j] = r0;
        aP[j] = hidden + (size_t)(rbase + r0 + lr) * Id + g8;
        int rb0 = (w & 3) * 8 + (w >> 2) * 64 + (j & 1) * 128 + (j >> 1) * 32;
        rbD[j] = rb0;
        size_t wr = (size_t)e * Hd + (size_t)ct * 256 + rb0 + lr;
        bP[j] = wd_b + wr * Id + g8;
    }

    f32x4 acc[8][4];
#pragma unroll
    for (int mi = 0; mi < 8; mi++)
#pragma unroll
        for (int n = 0; n < 4; n++) acc[mi][n] = (f32x4)0.f;

    ST_A0(0, 0); ST_B0(0, 0); ST_A1(0, 0); ST_B1(0, 0);
    ST_A0(1, BK); ST_B0(1, BK); ST_A1(1, BK);
    VM6_SB(); BAR();

    const int nt = Id / BK;   // 128
    for (int t = 0; t < nt; ++t) {
        const int bR = t & 1, bW = bR ^ 1;
        const int kN  = (t + 1 < nt ? t + 1 : nt - 1) * BK;
        const int kNN = (t + 2 < nt ? t + 2 : nt - 1) * BK;
        KTILE_BODY(bR, bW, kN, kNN);
    }
    asm volatile("s_waitcnt vmcnt(0)" ::: "memory");

#pragma unroll
    for (int mi = 0; mi < 8; mi++)
#pragma unroll
        for (int n = 0; n < 4; n++) {
            int col = ct * 256 + wn * 64 + n * 16 + c16;
#pragma unroll
            for (int q = 0; q < 4; q++) {
                int r = rbase + wm * 128 + mi * 16 + c4 * 4 + q;
                int tok = row_token[r];
                float gv = row_gate[r];
                if (gv != 0.f)
                    atomicAdd(&out[(size_t)tok * Hd + col], gv * acc[mi][n][q]);
            }
        }
}

// ================= f32-weight fused GEMMs (fallback if ws too small) =================

__global__ __launch_bounds__(256, 2)
void gemm1_f32_kernel(const unsigned short* __restrict__ xb,
                      const float* __restrict__ wgu,
                      const int* __restrict__ row_token,
                      const int* __restrict__ offsets,
                      unsigned short* __restrict__ hidden) {
    __shared__ unsigned short As[128][BK];
    __shared__ unsigned short Bg[128][BK];
    __shared__ unsigned short Bu[128][BK];

    const int rt = blockIdx.x, ct = blockIdx.y;
    const int rbase = rt * 128;
    if (rbase >= offsets[4]) return;
    int e = 3;
    if (rbase < offsets[1]) e = 0;
    else if (rbase < offsets[2]) e = 1;
    else if (rbase < offsets[3]) e = 2;

    const int tid = threadIdx.x;
    const int lane = tid & 63;
    const int wave = tid >> 6;
    const int wm = wave >> 1, wn = wave & 1;

    const unsigned short* asrc[4];
#pragma unroll
    for (int i2 = 0; i2 < 4; i2++) {
        int sgi = i2 * 4 + wave;
        int row = sgi * 8 + (lane >> 3);
        int g = (lane & 7) ^ (row & 7);
        int tok = row_token[rbase + row];
        asrc[i2] = xb + (size_t)tok * Hd + g * 8;
    }
    const int col = tid >> 1;
    const int half = tid & 1;
    const size_t grow = (size_t)e * (2 * Id) + (size_t)ct * 128 + col;
    const float* bsrc_g = wgu + grow * Hd + half * 32;
    const float* bsrc_u = wgu + (grow + (size_t)Id) * Hd + half * 32;
    const int csw = col & 7;

    f32x4 accg[4][4], accu[4][4];
#pragma unroll
    for (int m = 0; m < 4; m++)
#pragma unroll
        for (int n = 0; n < 4; n++) { accg[m][n] = (f32x4)0.f; accu[m][n] = (f32x4)0.f; }

    for (int k0 = 0; k0 < Hd; k0 += BK) {
        __syncthreads();
#pragma unroll
        for (int i2 = 0; i2 < 4; i2++) {
            int sgi = i2 * 4 + wave;
            gload_lds16(asrc[i2] + k0, &As[sgi * 8][0]);
        }
        {
            const float* pg = bsrc_g + k0;
            const float* pu = bsrc_u + k0;
            f32x4 vg[8], vu[8];
#pragma unroll
            for (int j = 0; j < 8; j++) vg[j] = *(const f32x4*)(pg + j * 4);
#pragma unroll
            for (int j = 0; j < 8; j++) vu[j] = *(const f32x4*)(pu + j * 4);
#pragma unroll
            for (int j = 0; j < 4; j++) {
                union { unsigned short u[8]; short8 v8; } wg_, wu_;
#pragma unroll
                for (int q = 0; q < 4; q++) {
                    wg_.u[q] = f2bf(vg[2 * j][q]); wg_.u[4 + q] = f2bf(vg[2 * j + 1][q]);
                    wu_.u[q] = f2bf(vu[2 * j][q]); wu_.u[4 + q] = f2bf(vu[2 * j + 1][q]);
                }
                int gs = (half * 4 + j) ^ csw;
                *(short8*)&Bg[col][gs * 8] = wg_.v8;
                *(short8*)&Bu[col][gs * 8] = wu_.v8;
            }
        }
        __syncthreads();
#pragma unroll
        for (int kk = 0; kk < 2; kk++) {
            short8 af[4], bgf[4], buf_[4];
#pragma unroll
            for (int m = 0; m < 4; m++) {
                int r = wm * 64 + m * 16 + (lane & 15);
                int slot = (kk * 4 + (lane >> 4)) ^ (r & 7);
                af[m] = *(const short8*)&As[r][slot * 8];
            }
#pragma unroll
            for (int n = 0; n < 4; n++) {
                int c = wn * 64 + n * 16 + (lane & 15);
                int slot = (kk * 4 + (lane >> 4)) ^ (c & 7);
                bgf[n] = *(const short8*)&Bg[c][slot * 8];
                buf_[n] = *(const short8*)&Bu[c][slot * 8];
            }
#pragma unroll
            for (int m = 0; m < 4; m++)
#pragma unroll
                for (int n = 0; n < 4; n++) {
                    accg[m][n] = __builtin_amdgcn_mfma_f32_16x16x32_bf16(af[m], bgf[n], accg[m][n], 0, 0, 0);
                    accu[m][n] = __builtin_amdgcn_mfma_f32_16x16x32_bf16(af[m], buf_[n], accu[m][n], 0, 0, 0);
                }
        }
    }
#pragma unroll
    for (int m = 0; m < 4; m++) {
#pragma unroll
        for (int n = 0; n < 4; n++) {
            int c = ct * 128 + wn * 64 + n * 16 + (lane & 15);
#pragma unroll
            for (int q = 0; q < 4; q++) {
                int r = rbase + wm * 64 + m * 16 + (lane >> 4) * 4 + q;
                float g = accg[m][n][q], u = accu[m][n][q];
                float hval = u * g / (1.f + expf(-g));
                hidden[(size_t)r * Id + c] = f2bf(hval);
            }
        }
    }
}

__global__ __launch_bounds__(256, 2)
void gemm2_f32_kernel(const unsigned short* __restrict__ hidden,
                      const float* __restrict__ wd,
                      const int* __restrict__ row_token,
                      const float* __restrict__ row_gate,
                      const int* __restrict__ offsets,
                      float* __restrict__ out) {
    __shared__ unsigned short As[128][BK];
    __shared__ unsigned short Bs[128][BK];

    const int rt = blockIdx.x, ct = blockIdx.y;
    const int rbase = rt * 128;
    if (rbase >= offsets[4]) return;
    int e = 3;
    if (rbase < offsets[1]) e = 0;
    else if (rbase < offsets[2]) e = 1;
    else if (rbase < offsets[3]) e = 2;

    const int tid = threadIdx.x;
    const int lane = tid & 63;
    const int wave = tid >> 6;
    const int wm = wave >> 1, wn = wave & 1;

    const unsigned short* asrc[4];
#pragma unroll
    for (int i2 = 0; i2 < 4; i2++) {
        int sgi = i2 * 4 + wave;
        int row = sgi * 8 + (lane >> 3);
        int g = (lane & 7) ^ (row & 7);
        asrc[i2] = hidden + (size_t)(rbase + row) * Id + g * 8;
    }
    const int col = tid >> 1;
    const int half = tid & 1;
    const float* bsrc = wd + ((size_t)e * Hd + (size_t)ct * 128 + col) * Id + half * 32;
    const int csw = col & 7;

    f32x4 acc[4][4];
#pragma unroll
    for (int m = 0; m < 4; m++)
#pragma unroll
        for (int n = 0; n < 4; n++) acc[m][n] = (f32x4)0.f;

    for (int k0 = 0; k0 < Id; k0 += BK) {
        __syncthreads();
#pragma unroll
        for (int i2 = 0; i2 < 4; i2++) {
            int sgi = i2 * 4 + wave;
            gload_lds16(asrc[i2] + k0, &As[sgi * 8][0]);
        }
        {
            const float* pb = bsrc + k0;
            f32x4 vb[8];
#pragma unroll
            for (int j = 0; j < 8; j++) vb[j] = *(const f32x4*)(pb + j * 4);
#pragma unroll
            for (int j = 0; j < 4; j++) {
                union { unsigned short u[8]; short8 v8; } wb_;
#pragma unroll
                for (int q = 0; q < 4; q++) {
                    wb_.u[q] = f2bf(vb[2 * j][q]); wb_.u[4 + q] = f2bf(vb[2 * j + 1][q]);
                }
                int gs = (half * 4 + j) ^ csw;
                *(short8*)&Bs[col][gs * 8] = wb_.v8;
            }
        }
        __syncthreads();
#pragma unroll
        for (int kk = 0; kk < 2; kk++) {
            short8 af[4], bf[4];
#pragma unroll
            for (int m = 0; m < 4; m++) {
                int r = wm * 64 + m * 16 + (lane & 15);
                int slot = (kk * 4 + (lane >> 4)) ^ (r & 7);
                af[m] = *(const short8*)&As[r][slot * 8];
            }
#pragma unroll
            for (int n = 0; n < 4; n++) {
                int c = wn * 64 + n * 16 + (lane & 15);
                int slot = (kk * 4 + (lane >> 4)) ^ (c & 7);
                bf[n] = *(const short8*)&Bs[c][slot * 8];
            }
#pragma unroll
            for (int m = 0; m < 4; m++)
#pragma unroll
                for (int n = 0; n < 4; n++)
                    acc[m][n] = __builtin_amdgcn_mfma_f32_16x16x32_bf16(af[m], bf[n], acc[m][n], 0, 0, 0);
        }
    }
#pragma unroll
    for (int m = 0; m < 4; m++) {
#pragma unroll
        for (int n = 0; n < 4; n++) {
            int c = ct * 128 + wn * 64 + n * 16 + (lane & 15);
#pragma unroll
            for (int q = 0; q < 4; q++) {
                int r = rbase + wm * 64 + m * 16 + (lane >> 4) * 4 + q;
                int tok = row_token[r];
                float gv = row_gate[r];
                if (gv != 0.f)
                    atomicAdd(&out[(size_t)tok * Hd + c], gv * acc[m][n][q]);
            }
        }
    }
}

extern "C" void kernel_launch(void* const* d_in, const int* in_sizes, int n_in,
                              void* d_out, int out_size, void* d_ws, size_t ws_size,
                              hipStream_t stream) {
    const float* x   = (const float*)d_in[0];
    const float* gw  = (const float*)d_in[1];
    const float* wgu = (const float*)d_in[2];
    const float* wd  = (const float*)d_in[3];
    float* out = (float*)d_out;

    const size_t n_wgu = (size_t)NE * 2 * Id * Hd;
    const size_t n_wd  = (size_t)NE * Hd * Id;

    char* ws = (char*)d_ws;
    size_t o = 0;
    auto alloc = [&](size_t bytes) { void* p = ws + o; o = (o + bytes + 255) & ~(size_t)255; return p; };
    unsigned short* xb      = (unsigned short*)alloc((size_t)S * Hd * 2);
    unsigned short* hidden  = (unsigned short*)alloc((size_t)RMAX * Id * 2);
    int*   row_token = (int*)alloc(RMAX * 4);
    float* row_gate  = (float*)alloc(RMAX * 4);
    int*   offsets   = (int*)alloc(8 * 4);
    int*   tok_e     = (int*)alloc(S * 2 * 4);
    float* tok_v     = (float*)alloc(S * 2 * 4);
    unsigned short* wgu_b = (unsigned short*)alloc(n_wgu * 2);
    unsigned short* wd_b  = (unsigned short*)alloc(n_wd * 2);
    const bool big = (ws_size >= o);

    hipMemsetAsync(d_out, 0, (size_t)S * Hd * 4, stream);

    if (big) {
        fused_pre_kernel<<<CVT1_BLKS + CVTX_BLKS + GATE_BLKS, 256, 0, stream>>>(
            x, gw, wgu, wgu_b, xb, tok_e, tok_v);
        route_kernel<<<1, 256, 0, stream>>>(tok_e, tok_v, row_token, row_gate, offsets);
        gemm1_8p_kernel<<<CVTW_BLKS + 1280, 512, 0, stream>>>(
            xb, wgu_b, wd, wd_b, row_token, offsets, hidden);
        gemm2_8p_kernel<<<dim3(RMAX / 256, Hd / 256), 512, 0, stream>>>(
            hidden, wd_b, row_token, row_gate, offsets, out);
    } else {
        gate_topk_kernel<<<S, 256, 0, stream>>>(x, gw, tok_e, tok_v);
        route_kernel<<<1, 256, 0, stream>>>(tok_e, tok_v, row_token, row_gate, offsets);
        cvt_bf16_kernel<<<1024, 256, 0, stream>>>(x, xb, (size_t)S * Hd / 16);
        gemm1_f32_kernel<<<dim3(RMAX / 128, Id / 128), 256, 0, stream>>>(
            xb, wgu, row_token, offsets, hidden);
        gemm2_f32_kernel<<<dim3(RMAX / 128, Hd / 128), 256, 0, stream>>>(
            hidden, wd, row_token, row_gate, offsets, out);
    }
}